// Round 4
// baseline (387.508 us; speedup 1.0000x reference)
//
#include <hip/hip_runtime.h>

#define NRES 512
#define NN   (NRES * NRES)
#define CZ   128

typedef __attribute__((ext_vector_type(8))) short bf16x8;  // 8 bf16 = 4 VGPRs (MFMA A/B frag)
typedef __attribute__((ext_vector_type(4))) short s16x4;   // 8-byte packed store
typedef __attribute__((ext_vector_type(4))) float f32x4;   // MFMA C/D frag

static __device__ __forceinline__ short f2bf(float f) {
  union { float f; unsigned u; } v; v.f = f;
  unsigned r = v.u + 0x7fffu + ((v.u >> 16) & 1u);  // round-nearest-even
  return (short)(r >> 16);
}

static __device__ __forceinline__ void gload_lds16(const void* g, void* l) {
  // async global->LDS, 16B/lane; LDS dest is wave-uniform base + lane*16
  __builtin_amdgcn_global_load_lds(
      (__attribute__((address_space(1))) const void*)g,
      (__attribute__((address_space(3))) void*)l, 16, 0, 0);
}

// ---------------------------------------------------------------------------
// K0: weights -> bf16, transposed to MFMA B-operand layout.
// ---------------------------------------------------------------------------
__global__ __launch_bounds__(256) void k_prep(const float* __restrict__ a_w,
                                              const float* __restrict__ b_w,
                                              const float* __restrict__ out_w,
                                              short* __restrict__ w_cat_t,
                                              short* __restrict__ w_out_t) {
  int idx = blockIdx.x * 256 + threadIdx.x;
  if (idx < 256 * 128) {
    int cc = idx >> 7, zz = idx & 127;
    float v = (cc < 128) ? a_w[zz * 128 + cc] : b_w[zz * 128 + (cc - 128)];
    w_cat_t[idx] = f2bf(v);
  } else if (idx < 256 * 128 + 128 * 128) {
    int i2 = idx - 256 * 128;
    int zz = i2 >> 7, cc = i2 & 127;
    w_out_t[i2] = f2bf(out_w[cc * 128 + zz]);
  }
}

// ---------------------------------------------------------------------------
// K1: LN (registers + 8-lane shuffle) + dual projection MFMA [64x128]@[128x256].
// v3: (a) XCD-chunked bijective block swizzle — consecutive swizzled blocks run
// on the SAME XCD, so their adjacent 128B channel-write runs merge in that
// XCD's L2 and drain to HBM row-sequentially (the v2 counters showed duration
// pinned at ~105us with occupancy 2x'd -> not latency-bound; scattered 128B
// writes at 512KB stride across XCDs are the remaining structural suspect).
// (b) launch_bounds (512,4): v2's (512,6)=85-reg budget spilled one float4 per
// thread (WRITE_SIZE +32MiB exactly = 4096*512*16B). 128-reg budget kills it;
// occupancy 24->16 waves/CU is proven irrelevant for this kernel.
// ---------------------------------------------------------------------------
__global__ __launch_bounds__(512, 4) void k_lnproj(const float* __restrict__ z,
                                                   const float* __restrict__ ln_w,
                                                   const float* __restrict__ ln_b,
                                                   const float* __restrict__ a_bias,
                                                   const float* __restrict__ b_bias,
                                                   const short* __restrict__ w_cat_t,
                                                   short* __restrict__ a_t,
                                                   short* __restrict__ b_t) {
  __shared__ short xb[64][136];  // +8 pad; reused as 8x per-wave transpose buffers

  const int tid = threadIdx.x;
  const int bid = (int)blockIdx.x;
  // bijective XCD-chunk swizzle: 4096 = 8 * 512; XCD k owns swizzled range [k*512,(k+1)*512)
  const int sb = ((bid & 7) << 9) | (bid >> 3);
  const int r0 = sb * 64;
  const int row = tid >> 3, seg = tid & 7;  // 8 threads per row (same-wave octet)

  // ---- LN phase, fully in registers ----
  const float4* zg = (const float4*)(z + (size_t)r0 * CZ);
  float4 v[4];
#pragma unroll
  for (int it = 0; it < 4; ++it) v[it] = zg[row * 32 + seg + it * 8];  // ch4 = seg + it*8

  float s = 0.f, s2 = 0.f;
#pragma unroll
  for (int it = 0; it < 4; ++it) {
    s  += v[it].x + v[it].y + v[it].z + v[it].w;
    s2 += v[it].x * v[it].x + v[it].y * v[it].y + v[it].z * v[it].z + v[it].w * v[it].w;
  }
  s  += __shfl_xor(s, 1);  s  += __shfl_xor(s, 2);  s  += __shfl_xor(s, 4);
  s2 += __shfl_xor(s2, 1); s2 += __shfl_xor(s2, 2); s2 += __shfl_xor(s2, 4);
  const float mu = s * (1.f / CZ);
  const float rstd = rsqrtf(s2 * (1.f / CZ) - mu * mu + 1e-5f);

  const float4* lw4 = (const float4*)ln_w;
  const float4* lb4 = (const float4*)ln_b;
#pragma unroll
  for (int it = 0; it < 4; ++it) {
    float4 wv = lw4[seg + it * 8], bv = lb4[seg + it * 8];
    s16x4 pk;
    pk[0] = f2bf((v[it].x - mu) * rstd * wv.x + bv.x);
    pk[1] = f2bf((v[it].y - mu) * rstd * wv.y + bv.y);
    pk[2] = f2bf((v[it].z - mu) * rstd * wv.z + bv.z);
    pk[3] = f2bf((v[it].w - mu) * rstd * wv.w + bv.w);
    *(s16x4*)&xb[row][seg * 4 + it * 32] = pk;
  }
  __syncthreads();

  // ---- MFMA phase: [64x128] @ [128x256], 8 waves x (64 rows x 32 cols) ----
  const int w = tid >> 6, l = tid & 63;
  const int q = l >> 4, n16 = l & 15;
  const f32x4 zf = {0.f, 0.f, 0.f, 0.f};
  f32x4 acc[4][2];
#pragma unroll
  for (int a = 0; a < 4; ++a)
#pragma unroll
    for (int b = 0; b < 2; ++b) acc[a][b] = zf;

#pragma unroll
  for (int kk = 0; kk < 4; ++kk) {
    bf16x8 af[4], bfv[2];
#pragma unroll
    for (int rt = 0; rt < 4; ++rt)
      af[rt] = *(const bf16x8*)&xb[rt * 16 + n16][kk * 32 + q * 8];
#pragma unroll
    for (int ct = 0; ct < 2; ++ct) {
      int col = w * 32 + ct * 16 + n16;   // 0..255 (a|b concat); weights are L2-hot
      bfv[ct] = *(const bf16x8*)&w_cat_t[col * 128 + kk * 32 + q * 8];
    }
#pragma unroll
    for (int rt = 0; rt < 4; ++rt)
#pragma unroll
      for (int ct = 0; ct < 2; ++ct)
        acc[rt][ct] = __builtin_amdgcn_mfma_f32_16x16x32_bf16(af[rt], bfv[ct], acc[rt][ct], 0, 0, 0);
  }

  // ---- epilogue: per-wave LDS transpose, then coalesced stores ----
  __syncthreads();  // all waves done reading xb; safe to reuse as transpose bufs
  short* tb = &xb[0][0] + w * (16 * 66);  // per-wave 16ch x (64+2) rows buffer
  // a_t/b_t are contiguous in ws: col>=128 lands in b_t automatically
#pragma unroll
  for (int ct = 0; ct < 2; ++ct) {
    const int col = w * 32 + ct * 16 + n16;
    const int ch = col & 127;
    const float bias = (col < 128) ? a_bias[ch] : b_bias[ch];
#pragma unroll
    for (int rt = 0; rt < 4; ++rt) {
      s16x4 pk;
#pragma unroll
      for (int rg = 0; rg < 4; ++rg) pk[rg] = f2bf(acc[rt][ct][rg] + bias);
      *(s16x4*)&tb[n16 * 66 + rt * 16 + q * 4] = pk;  // [ch16][r64+2]
    }
    // wave-synchronous: same-wave DS ops retire in order; read back coalesced
#pragma unroll
    for (int i = 0; i < 2; ++i) {
      int ch_l = i * 8 + (l >> 3);
      int rseg = l & 7;
      bf16x8 t = *(const bf16x8*)&tb[ch_l * 66 + rseg * 8];
      int colg = w * 32 + ct * 16 + ch_l;
      *(bf16x8*)&a_t[(size_t)colg * NN + r0 + rseg * 8] = t;  // 128B run per channel
    }
  }
}

// ---------------------------------------------------------------------------
// K2: per-channel C_c = A_c * B_c^T, 128x128 tile, K=512 in 8 stages of BK=64.
// MFMA operands swapped (D = [j][i]) so the epilogue can pack b64 into a
// 128x128 LDS tile (union over As/Bs, stride 134: <=2-way banks both phases),
// then store u with fully-coalesced dwordx4 (8 instrs/thread, 256B runs).
// ---------------------------------------------------------------------------
__global__ __launch_bounds__(256, 3) void k_einsum(const short* __restrict__ a_t,
                                                   const short* __restrict__ b_t,
                                                   short* __restrict__ u_bf) {
  __shared__ short smem[128 * 134];        // 34.3 KB; As/Bs live in first 32 KB
  short* As = smem;                        // [128][64]
  short* Bs = smem + 128 * 64;             // [128][64]

  const int bid = blockIdx.x;
  const int xcd = bid & 7;
  const int g = bid >> 3;
  const int c = (xcd << 4) | (g >> 4);     // 0..127; 16 consecutive blocks/XCD per channel
  const int t = g & 15;
  const int ti = t >> 2, tj = t & 3;

  const short* Ab = a_t + (size_t)c * NN + (size_t)(ti * 128) * NRES;
  const short* Bb = b_t + (size_t)c * NN + (size_t)(tj * 128) * NRES;

  const int tid = threadIdx.x, w = tid >> 6, l = tid & 63;
  const int q = l >> 4, n16 = l & 15;
  const int wr = w >> 1, wc = w & 1;

  const int srow = l >> 3;                 // row within 8-row staging group
  const int schk = l & 7;                  // LDS chunk slot (HW: base + lane*16)
  const int gchk = schk ^ srow;            // swizzled global source chunk

  const f32x4 zf = {0.f, 0.f, 0.f, 0.f};
  f32x4 acc[4][4];                         // [jt][it]
#pragma unroll
  for (int a = 0; a < 4; ++a)
#pragma unroll
    for (int b = 0; b < 4; ++b) acc[a][b] = zf;

  for (int st = 0; st < 8; ++st) {
    const int k0 = st * 64;
    __syncthreads();  // prev stage's frag reads done before overwrite
#pragma unroll
    for (int i = 0; i < 4; ++i) {
      int r = w * 32 + i * 8 + srow;
      gload_lds16(Ab + (size_t)r * NRES + k0 + gchk * 8, &As[(w * 32 + i * 8) * 64 + l * 8]);
      gload_lds16(Bb + (size_t)r * NRES + k0 + gchk * 8, &Bs[(w * 32 + i * 8) * 64 + l * 8]);
    }
    __syncthreads();  // drains vmcnt per barrier semantics

#pragma unroll
    for (int kk = 0; kk < 2; ++kk) {
      bf16x8 af[4], bfv[4];
#pragma unroll
      for (int it = 0; it < 4; ++it) {
        int m = wr * 64 + it * 16 + n16;
        af[it] = *(const bf16x8*)&As[m * 64 + ((kk * 4 + q) ^ (m & 7)) * 8];
      }
#pragma unroll
      for (int jt = 0; jt < 4; ++jt) {
        int n = wc * 64 + jt * 16 + n16;
        bfv[jt] = *(const bf16x8*)&Bs[n * 64 + ((kk * 4 + q) ^ (n & 7)) * 8];
      }
      // operands swapped: D[m=j][n=i] -> lane holds 4 consecutive j per i
#pragma unroll
      for (int jt = 0; jt < 4; ++jt)
#pragma unroll
        for (int it = 0; it < 4; ++it)
          acc[jt][it] = __builtin_amdgcn_mfma_f32_16x16x32_bf16(bfv[jt], af[it], acc[jt][it], 0, 0, 0);
    }
  }

  // ---- epilogue: acc -> LDS tile [i][j] (stride 134) -> coalesced stores ----
  __syncthreads();  // all MFMA LDS reads done; reuse smem as the u-tile
  const float sc = 0.04419417382415922f;  // 1/sqrt(512)
#pragma unroll
  for (int jt = 0; jt < 4; ++jt)
#pragma unroll
    for (int it = 0; it < 4; ++it) {
      s16x4 pk;
#pragma unroll
      for (int rg = 0; rg < 4; ++rg) pk[rg] = f2bf(acc[jt][it][rg] * sc);
      int il = wr * 64 + it * 16 + n16;          // column of D = i
      int jl = wc * 64 + jt * 16 + q * 4;        // row of D = j (4 consecutive)
      *(s16x4*)&smem[il * 134 + jl] = pk;        // b64, <=2-way banks
    }
  __syncthreads();

  short* ub = u_bf + (size_t)c * NN + (size_t)(ti * 128) * NRES + tj * 128;
#pragma unroll
  for (int vv = 0; vv < 8; ++vv) {
    int CH = vv * 256 + tid;                     // 0..2047
    int i = CH >> 4, js = CH & 15;
    bf16x8 tv = *(const bf16x8*)&smem[i * 134 + js * 8];
    *(bf16x8*)&ub[(size_t)i * NRES + js * 8] = tv;  // 256B contiguous runs
  }
}

// ---------------------------------------------------------------------------
// K3: out[m][z] = sum_c u[c][m] * out_w[c][z] + out_b[z], masked.
// v3: XCD-chunked block swizzle so consecutive 64KB out-regions drain from the
// same XCD's L2 (out writes are scattered 64B lines within a block but dense
// across adjacent blocks).
// ---------------------------------------------------------------------------
#define US_S 130
__global__ __launch_bounds__(256, 3) void k_outproj(const short* __restrict__ u_bf,
                                                    const short* __restrict__ w_out_t,
                                                    const float* __restrict__ out_b,
                                                    const int* __restrict__ mask,
                                                    float* __restrict__ out) {
  __shared__ short Us[128 * US_S];

  const int bid = (int)blockIdx.x;
  // bijective XCD-chunk swizzle: 2048 = 8 * 256
  const int sb = ((bid & 7) << 8) | (bid >> 3);
  const int m0 = sb * 128;
  const int tid = threadIdx.x, w = tid >> 6, l = tid & 63;
  const int q = l >> 4, n16 = l & 15;
  const int wz = w >> 1, wm = w & 1;

  // ---- coalesced staging: lanes along m, 4 c-rows per wave-instr ----
  {
    const int mseg = tid & 15;         // 16B chunk along m
    const int cb = tid >> 4;           // 0..15
#pragma unroll
    for (int it = 0; it < 8; ++it) {
      int cc = it * 16 + cb;
      bf16x8 vv = *(const bf16x8*)(u_bf + (size_t)cc * NN + m0 + mseg * 8);
      int base = cc * US_S + mseg * 8;
#pragma unroll
      for (int wi = 0; wi < 4; ++wi) {
        int pk = ((int)(unsigned short)vv[2 * wi + 1] << 16) | (unsigned short)vv[2 * wi];
        *(int*)&Us[base + 2 * wi] = pk;
      }
    }
  }
  __syncthreads();

  const f32x4 zf = {0.f, 0.f, 0.f, 0.f};
  f32x4 acc[4][4];  // [rt: z-sub][ct: m-sub]
#pragma unroll
  for (int a = 0; a < 4; ++a)
#pragma unroll
    for (int b = 0; b < 4; ++b) acc[a][b] = zf;

#pragma unroll
  for (int kk = 0; kk < 4; ++kk) {
    bf16x8 af[4];  // A[z][c] = w_out_t
#pragma unroll
    for (int rt = 0; rt < 4; ++rt) {
      int zz = wz * 64 + rt * 16 + n16;
      af[rt] = *(const bf16x8*)&w_out_t[zz * 128 + kk * 32 + q * 8];
    }
    bf16x8 bfv[4];  // B[c][m] from Us (8 x u16 gather, broadcast-friendly)
#pragma unroll
    for (int ct = 0; ct < 4; ++ct) {
      int mm = wm * 64 + ct * 16 + n16;
      int c0 = kk * 32 + q * 8;
      bf16x8 tv;
#pragma unroll
      for (int j = 0; j < 8; ++j) tv[j] = Us[(c0 + j) * US_S + mm];
      bfv[ct] = tv;
    }
#pragma unroll
    for (int rt = 0; rt < 4; ++rt)
#pragma unroll
      for (int ct = 0; ct < 4; ++ct)
        acc[rt][ct] = __builtin_amdgcn_mfma_f32_16x16x32_bf16(af[rt], bfv[ct], acc[rt][ct], 0, 0, 0);
  }

  // ---- epilogue: D[z][m]; lane holds z0..z0+3 for column m -> float4 store ----
  const int i_blk = m0 >> 9;
  const int j0 = m0 & 511;
  const int mi = mask[i_blk];
#pragma unroll
  for (int ct = 0; ct < 4; ++ct) {
    int mm = wm * 64 + ct * 16 + n16;
    int on = (mi != 0) && (mask[j0 + mm] != 0);
#pragma unroll
    for (int rt = 0; rt < 4; ++rt) {
      int z0 = wz * 64 + rt * 16 + q * 4;
      float4 bias = *(const float4*)&out_b[z0];
      float4 r;
      r.x = on ? acc[rt][ct][0] + bias.x : 0.f;
      r.y = on ? acc[rt][ct][1] + bias.y : 0.f;
      r.z = on ? acc[rt][ct][2] + bias.z : 0.f;
      r.w = on ? acc[rt][ct][3] + bias.w : 0.f;
      *(float4*)&out[(size_t)(m0 + mm) * CZ + z0] = r;
    }
  }
}

// ---------------------------------------------------------------------------
extern "C" void kernel_launch(void* const* d_in, const int* in_sizes, int n_in,
                              void* d_out, int out_size, void* d_ws, size_t ws_size,
                              hipStream_t stream) {
  const float* z     = (const float*)d_in[0];
  const int*   mask  = (const int*)d_in[1];
  const float* ln_w  = (const float*)d_in[2];
  const float* ln_b  = (const float*)d_in[3];
  const float* a_w   = (const float*)d_in[4];
  const float* a_b   = (const float*)d_in[5];
  const float* b_w   = (const float*)d_in[6];
  const float* b_b   = (const float*)d_in[7];
  const float* out_w = (const float*)d_in[8];
  const float* out_b = (const float*)d_in[9];
  float* out = (float*)d_out;

  char* p = (char*)d_ws;
  short* w_cat_t = (short*)p; p += (size_t)256 * 128 * 2;
  short* w_out_t = (short*)p; p += (size_t)128 * 128 * 2;
  short* a_t  = (short*)p; p += (size_t)NN * 128 * 2;   // b_t contiguous after a_t
  short* b_t  = (short*)p; p += (size_t)NN * 128 * 2;
  short* u_bf = (short*)p; p += (size_t)NN * 128 * 2;

  hipLaunchKernelGGL(k_prep,    dim3(192),  dim3(256), 0, stream, a_w, b_w, out_w, w_cat_t, w_out_t);
  hipLaunchKernelGGL(k_lnproj,  dim3(4096), dim3(512), 0, stream, z, ln_w, ln_b, a_b, b_b, w_cat_t, a_t, b_t);
  hipLaunchKernelGGL(k_einsum,  dim3(2048), dim3(256), 0, stream, a_t, b_t, u_bf);
  hipLaunchKernelGGL(k_outproj, dim3(2048), dim3(256), 0, stream, u_bf, w_out_t, out_b, mask, out);
}

// Round 5
// 374.370 us; speedup vs baseline: 1.0351x; 1.0351x over previous
//
#include <hip/hip_runtime.h>

#define NRES 512
#define NN   (NRES * NRES)
#define CZ   128

typedef __attribute__((ext_vector_type(8))) short bf16x8;  // 8 bf16 = 4 VGPRs (MFMA A/B frag)
typedef __attribute__((ext_vector_type(4))) short s16x4;   // 8-byte packed store
typedef __attribute__((ext_vector_type(4))) float f32x4;   // MFMA C/D frag

static __device__ __forceinline__ short f2bf(float f) {
  union { float f; unsigned u; } v; v.f = f;
  unsigned r = v.u + 0x7fffu + ((v.u >> 16) & 1u);  // round-nearest-even
  return (short)(r >> 16);
}

static __device__ __forceinline__ void gload_lds16(const void* g, void* l) {
  // async global->LDS, 16B/lane; LDS dest is wave-uniform base + lane*16
  __builtin_amdgcn_global_load_lds(
      (__attribute__((address_space(1))) const void*)g,
      (__attribute__((address_space(3))) void*)l, 16, 0, 0);
}

// ---------------------------------------------------------------------------
// K0: weights -> bf16, transposed to MFMA B-operand layout.
// ---------------------------------------------------------------------------
__global__ __launch_bounds__(256) void k_prep(const float* __restrict__ a_w,
                                              const float* __restrict__ b_w,
                                              const float* __restrict__ out_w,
                                              short* __restrict__ w_cat_t,
                                              short* __restrict__ w_out_t) {
  int idx = blockIdx.x * 256 + threadIdx.x;
  if (idx < 256 * 128) {
    int cc = idx >> 7, zz = idx & 127;
    float v = (cc < 128) ? a_w[zz * 128 + cc] : b_w[zz * 128 + (cc - 128)];
    w_cat_t[idx] = f2bf(v);
  } else if (idx < 256 * 128 + 128 * 128) {
    int i2 = idx - 256 * 128;
    int zz = i2 >> 7, cc = i2 & 127;
    w_out_t[i2] = f2bf(out_w[cc * 128 + zz]);
  }
}

// ---------------------------------------------------------------------------
// K1 v4: 128-row blocks (grid 2048). Evidence: duration invariant (~105us)
// across occupancy 12->24 waves AND +45MB spill traffic -> cost scales with
// the COUNT of scattered write bursts (4096x256 x 128B runs @512KB stride),
// not bytes. This version halves burst count / doubles run length:
//   2 sub-tiles of {LN(64 rows) -> MFMA 64x256} with outputs parked in 32
//   VGPRs, then a 2-round epilogue via a [128ch][130] LDS stage storing
//   256B-contiguous runs per channel (16 lanes x 16B, 4 ch/instr).
// XCD swizzle on this kernel REVERTED (round-4: cost 10us).
// LDS 17.4+33.3=50.7KB -> 3 blocks/CU.
// ---------------------------------------------------------------------------
__global__ __launch_bounds__(512, 4) void k_lnproj(const float* __restrict__ z,
                                                   const float* __restrict__ ln_w,
                                                   const float* __restrict__ ln_b,
                                                   const float* __restrict__ a_bias,
                                                   const float* __restrict__ b_bias,
                                                   const short* __restrict__ w_cat_t,
                                                   short* __restrict__ a_t,
                                                   short* __restrict__ b_t) {
  __shared__ short xb[64][136];       // LN/MFMA staging per sub-tile (17.4 KB)
  __shared__ short stage[128 * 130];  // channel-group store staging (33.3 KB)

  const int tid = threadIdx.x;
  const int r0 = (int)blockIdx.x * 128;
  const int row = tid >> 3, seg8 = tid & 7;  // 8 threads per row (same-wave octet)
  const int w = tid >> 6, l = tid & 63;
  const int q = l >> 4, n16 = l & 15;

  s16x4 park[2][2][4];  // [sub][ct][rt] bf16 outputs, 32 VGPRs

#pragma unroll
  for (int sub = 0; sub < 2; ++sub) {
    const int rs = r0 + sub * 64;

    // ---- LN phase, fully in registers ----
    const float4* zg = (const float4*)(z + (size_t)rs * CZ);
    float4 v[4];
#pragma unroll
    for (int it = 0; it < 4; ++it) v[it] = zg[row * 32 + seg8 + it * 8];

    float s = 0.f, s2 = 0.f;
#pragma unroll
    for (int it = 0; it < 4; ++it) {
      s  += v[it].x + v[it].y + v[it].z + v[it].w;
      s2 += v[it].x * v[it].x + v[it].y * v[it].y + v[it].z * v[it].z + v[it].w * v[it].w;
    }
    s  += __shfl_xor(s, 1);  s  += __shfl_xor(s, 2);  s  += __shfl_xor(s, 4);
    s2 += __shfl_xor(s2, 1); s2 += __shfl_xor(s2, 2); s2 += __shfl_xor(s2, 4);
    const float mu = s * (1.f / CZ);
    const float rstd = rsqrtf(s2 * (1.f / CZ) - mu * mu + 1e-5f);

    const float4* lw4 = (const float4*)ln_w;
    const float4* lb4 = (const float4*)ln_b;
#pragma unroll
    for (int it = 0; it < 4; ++it) {
      float4 wv = lw4[seg8 + it * 8], bv = lb4[seg8 + it * 8];
      s16x4 pk;
      pk[0] = f2bf((v[it].x - mu) * rstd * wv.x + bv.x);
      pk[1] = f2bf((v[it].y - mu) * rstd * wv.y + bv.y);
      pk[2] = f2bf((v[it].z - mu) * rstd * wv.z + bv.z);
      pk[3] = f2bf((v[it].w - mu) * rstd * wv.w + bv.w);
      *(s16x4*)&xb[row][seg8 * 4 + it * 32] = pk;
    }
    __syncthreads();

    // ---- MFMA: [64x128] @ [128x256], 8 waves x (64 rows x 32 cols) ----
    f32x4 acc[4][2];
    const f32x4 zf = {0.f, 0.f, 0.f, 0.f};
#pragma unroll
    for (int a = 0; a < 4; ++a)
#pragma unroll
      for (int b = 0; b < 2; ++b) acc[a][b] = zf;

#pragma unroll
    for (int kk = 0; kk < 4; ++kk) {
      bf16x8 af[4], bfv[2];
#pragma unroll
      for (int rt = 0; rt < 4; ++rt)
        af[rt] = *(const bf16x8*)&xb[rt * 16 + n16][kk * 32 + q * 8];
#pragma unroll
      for (int ct = 0; ct < 2; ++ct) {
        int col = w * 32 + ct * 16 + n16;   // 0..255 (a|b concat); weights L2-hot
        bfv[ct] = *(const bf16x8*)&w_cat_t[col * 128 + kk * 32 + q * 8];
      }
#pragma unroll
      for (int rt = 0; rt < 4; ++rt)
#pragma unroll
        for (int ct = 0; ct < 2; ++ct)
          acc[rt][ct] = __builtin_amdgcn_mfma_f32_16x16x32_bf16(af[rt], bfv[ct], acc[rt][ct], 0, 0, 0);
    }

    // ---- park (bias + bf16 convert); acc dies here ----
#pragma unroll
    for (int ct = 0; ct < 2; ++ct) {
      const int col = w * 32 + ct * 16 + n16;
      const int ch = col & 127;
      const float bias = (col < 128) ? a_bias[ch] : b_bias[ch];
#pragma unroll
      for (int rt = 0; rt < 4; ++rt) {
        s16x4 pk;
#pragma unroll
        for (int rg = 0; rg < 4; ++rg) pk[rg] = f2bf(acc[rt][ct][rg] + bias);
        park[sub][ct][rt] = pk;
      }
    }
    __syncthreads();  // xb reads done before next sub's LN overwrites
  }

  // ---- epilogue: 2 channel-group rounds through the stage buffer ----
  // round g covers global cols g*128..g*128+127 (g=0 -> a_t, g=1 -> b_t;
  // contiguous in ws so a_t base works for both).
  const int seg = tid & 15, cq = tid >> 4;  // store mapping: 16 segs x 32 ch-slots
#pragma unroll
  for (int g = 0; g < 2; ++g) {
    if ((w >> 2) == g) {  // the 4 waves owning these 128 cols
#pragma unroll
      for (int sub = 0; sub < 2; ++sub)
#pragma unroll
        for (int ct = 0; ct < 2; ++ct)
#pragma unroll
          for (int rt = 0; rt < 4; ++rt) {
            int ch_local = (w & 3) * 32 + ct * 16 + n16;   // 0..127
            int row_local = sub * 64 + rt * 16 + q * 4;    // 0..124
            *(s16x4*)&stage[ch_local * 130 + row_local] = park[sub][ct][rt];
          }
    }
    __syncthreads();
#pragma unroll
    for (int it = 0; it < 4; ++it) {
      int ch_l = it * 32 + cq;                             // 0..127
      bf16x8 t = *(const bf16x8*)&stage[ch_l * 130 + seg * 8];
      int ch_global = g * 128 + ch_l;
      // 256B contiguous run per channel (16 lanes x 16B), 4 ch per wave-instr
      *(bf16x8*)&a_t[(size_t)ch_global * NN + r0 + seg * 8] = t;
    }
    __syncthreads();  // stage reuse for g=1
  }
}

// ---------------------------------------------------------------------------
// K2: per-channel C_c = A_c * B_c^T, 128x128 tile, K=512 in 8 stages of BK=64.
// MFMA operands swapped (D = [j][i]) so the epilogue can pack b64 into a
// 128x128 LDS tile (union over As/Bs, stride 134: <=2-way banks both phases),
// then store u with fully-coalesced dwordx4 (8 instrs/thread, 256B runs).
// ---------------------------------------------------------------------------
__global__ __launch_bounds__(256, 3) void k_einsum(const short* __restrict__ a_t,
                                                   const short* __restrict__ b_t,
                                                   short* __restrict__ u_bf) {
  __shared__ short smem[128 * 134];        // 34.3 KB; As/Bs live in first 32 KB
  short* As = smem;                        // [128][64]
  short* Bs = smem + 128 * 64;             // [128][64]

  const int bid = blockIdx.x;
  const int xcd = bid & 7;
  const int g = bid >> 3;
  const int c = (xcd << 4) | (g >> 4);     // 0..127; 16 consecutive blocks/XCD per channel
  const int t = g & 15;
  const int ti = t >> 2, tj = t & 3;

  const short* Ab = a_t + (size_t)c * NN + (size_t)(ti * 128) * NRES;
  const short* Bb = b_t + (size_t)c * NN + (size_t)(tj * 128) * NRES;

  const int tid = threadIdx.x, w = tid >> 6, l = tid & 63;
  const int q = l >> 4, n16 = l & 15;
  const int wr = w >> 1, wc = w & 1;

  const int srow = l >> 3;                 // row within 8-row staging group
  const int schk = l & 7;                  // LDS chunk slot (HW: base + lane*16)
  const int gchk = schk ^ srow;            // swizzled global source chunk

  const f32x4 zf = {0.f, 0.f, 0.f, 0.f};
  f32x4 acc[4][4];                         // [jt][it]
#pragma unroll
  for (int a = 0; a < 4; ++a)
#pragma unroll
    for (int b = 0; b < 4; ++b) acc[a][b] = zf;

  for (int st = 0; st < 8; ++st) {
    const int k0 = st * 64;
    __syncthreads();  // prev stage's frag reads done before overwrite
#pragma unroll
    for (int i = 0; i < 4; ++i) {
      int r = w * 32 + i * 8 + srow;
      gload_lds16(Ab + (size_t)r * NRES + k0 + gchk * 8, &As[(w * 32 + i * 8) * 64 + l * 8]);
      gload_lds16(Bb + (size_t)r * NRES + k0 + gchk * 8, &Bs[(w * 32 + i * 8) * 64 + l * 8]);
    }
    __syncthreads();  // drains vmcnt per barrier semantics

#pragma unroll
    for (int kk = 0; kk < 2; ++kk) {
      bf16x8 af[4], bfv[4];
#pragma unroll
      for (int it = 0; it < 4; ++it) {
        int m = wr * 64 + it * 16 + n16;
        af[it] = *(const bf16x8*)&As[m * 64 + ((kk * 4 + q) ^ (m & 7)) * 8];
      }
#pragma unroll
      for (int jt = 0; jt < 4; ++jt) {
        int n = wc * 64 + jt * 16 + n16;
        bfv[jt] = *(const bf16x8*)&Bs[n * 64 + ((kk * 4 + q) ^ (n & 7)) * 8];
      }
      // operands swapped: D[m=j][n=i] -> lane holds 4 consecutive j per i
#pragma unroll
      for (int jt = 0; jt < 4; ++jt)
#pragma unroll
        for (int it = 0; it < 4; ++it)
          acc[jt][it] = __builtin_amdgcn_mfma_f32_16x16x32_bf16(bfv[jt], af[it], acc[jt][it], 0, 0, 0);
    }
  }

  // ---- epilogue: acc -> LDS tile [i][j] (stride 134) -> coalesced stores ----
  __syncthreads();  // all MFMA LDS reads done; reuse smem as the u-tile
  const float sc = 0.04419417382415922f;  // 1/sqrt(512)
#pragma unroll
  for (int jt = 0; jt < 4; ++jt)
#pragma unroll
    for (int it = 0; it < 4; ++it) {
      s16x4 pk;
#pragma unroll
      for (int rg = 0; rg < 4; ++rg) pk[rg] = f2bf(acc[jt][it][rg] * sc);
      int il = wr * 64 + it * 16 + n16;          // column of D = i
      int jl = wc * 64 + jt * 16 + q * 4;        // row of D = j (4 consecutive)
      *(s16x4*)&smem[il * 134 + jl] = pk;        // b64, <=2-way banks
    }
  __syncthreads();

  short* ub = u_bf + (size_t)c * NN + (size_t)(ti * 128) * NRES + tj * 128;
#pragma unroll
  for (int vv = 0; vv < 8; ++vv) {
    int CH = vv * 256 + tid;                     // 0..2047
    int i = CH >> 4, js = CH & 15;
    bf16x8 tv = *(const bf16x8*)&smem[i * 134 + js * 8];
    *(bf16x8*)&ub[(size_t)i * NRES + js * 8] = tv;  // 256B contiguous runs
  }
}

// ---------------------------------------------------------------------------
// K3: out[m][z] = sum_c u[c][m] * out_w[c][z] + out_b[z], masked.
// Keeps v3's XCD-chunked swizzle (weak evidence it helped ~8us; isolated
// lnproj change this round for attribution).
// ---------------------------------------------------------------------------
#define US_S 130
__global__ __launch_bounds__(256, 3) void k_outproj(const short* __restrict__ u_bf,
                                                    const short* __restrict__ w_out_t,
                                                    const float* __restrict__ out_b,
                                                    const int* __restrict__ mask,
                                                    float* __restrict__ out) {
  __shared__ short Us[128 * US_S];

  const int bid = (int)blockIdx.x;
  // bijective XCD-chunk swizzle: 2048 = 8 * 256
  const int sb = ((bid & 7) << 8) | (bid >> 3);
  const int m0 = sb * 128;
  const int tid = threadIdx.x, w = tid >> 6, l = tid & 63;
  const int q = l >> 4, n16 = l & 15;
  const int wz = w >> 1, wm = w & 1;

  // ---- coalesced staging: lanes along m, 4 c-rows per wave-instr ----
  {
    const int mseg = tid & 15;         // 16B chunk along m
    const int cb = tid >> 4;           // 0..15
#pragma unroll
    for (int it = 0; it < 8; ++it) {
      int cc = it * 16 + cb;
      bf16x8 vv = *(const bf16x8*)(u_bf + (size_t)cc * NN + m0 + mseg * 8);
      int base = cc * US_S + mseg * 8;
#pragma unroll
      for (int wi = 0; wi < 4; ++wi) {
        int pk = ((int)(unsigned short)vv[2 * wi + 1] << 16) | (unsigned short)vv[2 * wi];
        *(int*)&Us[base + 2 * wi] = pk;
      }
    }
  }
  __syncthreads();

  const f32x4 zf = {0.f, 0.f, 0.f, 0.f};
  f32x4 acc[4][4];  // [rt: z-sub][ct: m-sub]
#pragma unroll
  for (int a = 0; a < 4; ++a)
#pragma unroll
    for (int b = 0; b < 4; ++b) acc[a][b] = zf;

#pragma unroll
  for (int kk = 0; kk < 4; ++kk) {
    bf16x8 af[4];  // A[z][c] = w_out_t
#pragma unroll
    for (int rt = 0; rt < 4; ++rt) {
      int zz = wz * 64 + rt * 16 + n16;
      af[rt] = *(const bf16x8*)&w_out_t[zz * 128 + kk * 32 + q * 8];
    }
    bf16x8 bfv[4];  // B[c][m] from Us (8 x u16 gather, broadcast-friendly)
#pragma unroll
    for (int ct = 0; ct < 4; ++ct) {
      int mm = wm * 64 + ct * 16 + n16;
      int c0 = kk * 32 + q * 8;
      bf16x8 tv;
#pragma unroll
      for (int j = 0; j < 8; ++j) tv[j] = Us[(c0 + j) * US_S + mm];
      bfv[ct] = tv;
    }
#pragma unroll
    for (int rt = 0; rt < 4; ++rt)
#pragma unroll
      for (int ct = 0; ct < 4; ++ct)
        acc[rt][ct] = __builtin_amdgcn_mfma_f32_16x16x32_bf16(af[rt], bfv[ct], acc[rt][ct], 0, 0, 0);
  }

  // ---- epilogue: D[z][m]; lane holds z0..z0+3 for column m -> float4 store ----
  const int i_blk = m0 >> 9;
  const int j0 = m0 & 511;
  const int mi = mask[i_blk];
#pragma unroll
  for (int ct = 0; ct < 4; ++ct) {
    int mm = wm * 64 + ct * 16 + n16;
    int on = (mi != 0) && (mask[j0 + mm] != 0);
#pragma unroll
    for (int rt = 0; rt < 4; ++rt) {
      int z0 = wz * 64 + rt * 16 + q * 4;
      float4 bias = *(const float4*)&out_b[z0];
      float4 r;
      r.x = on ? acc[rt][ct][0] + bias.x : 0.f;
      r.y = on ? acc[rt][ct][1] + bias.y : 0.f;
      r.z = on ? acc[rt][ct][2] + bias.z : 0.f;
      r.w = on ? acc[rt][ct][3] + bias.w : 0.f;
      *(float4*)&out[(size_t)(m0 + mm) * CZ + z0] = r;
    }
  }
}

// ---------------------------------------------------------------------------
extern "C" void kernel_launch(void* const* d_in, const int* in_sizes, int n_in,
                              void* d_out, int out_size, void* d_ws, size_t ws_size,
                              hipStream_t stream) {
  const float* z     = (const float*)d_in[0];
  const int*   mask  = (const int*)d_in[1];
  const float* ln_w  = (const float*)d_in[2];
  const float* ln_b  = (const float*)d_in[3];
  const float* a_w   = (const float*)d_in[4];
  const float* a_b   = (const float*)d_in[5];
  const float* b_w   = (const float*)d_in[6];
  const float* b_b   = (const float*)d_in[7];
  const float* out_w = (const float*)d_in[8];
  const float* out_b = (const float*)d_in[9];
  float* out = (float*)d_out;

  char* p = (char*)d_ws;
  short* w_cat_t = (short*)p; p += (size_t)256 * 128 * 2;
  short* w_out_t = (short*)p; p += (size_t)128 * 128 * 2;
  short* a_t  = (short*)p; p += (size_t)NN * 128 * 2;   // b_t contiguous after a_t
  short* b_t  = (short*)p; p += (size_t)NN * 128 * 2;
  short* u_bf = (short*)p; p += (size_t)NN * 128 * 2;

  hipLaunchKernelGGL(k_prep,    dim3(192),  dim3(256), 0, stream, a_w, b_w, out_w, w_cat_t, w_out_t);
  hipLaunchKernelGGL(k_lnproj,  dim3(2048), dim3(512), 0, stream, z, ln_w, ln_b, a_b, b_b, w_cat_t, a_t, b_t);
  hipLaunchKernelGGL(k_einsum,  dim3(2048), dim3(256), 0, stream, a_t, b_t, u_bf);
  hipLaunchKernelGGL(k_outproj, dim3(2048), dim3(256), 0, stream, u_bf, w_out_t, out_b, mask, out);
}